// Round 8
// baseline (514.351 us; speedup 1.0000x reference)
//
#include <hip/hip_runtime.h>

#define DEV __device__ __forceinline__

typedef float f32x4 __attribute__((ext_vector_type(4)));
typedef short s16x8 __attribute__((ext_vector_type(8)));
typedef short s16x4 __attribute__((ext_vector_type(4)));

// ---------- scalar helpers ----------
DEV unsigned short f2bf(float f){
  unsigned int u = __float_as_uint(f);
  u += 0x7fffu + ((u>>16)&1u);
  return (unsigned short)(u>>16);
}
DEV float bf2f(unsigned short h){ return __uint_as_float(((unsigned int)h)<<16); }

#if __has_builtin(__builtin_amdgcn_rcpf)
DEV float frcp_(float x){ return __builtin_amdgcn_rcpf(x); }
#else
DEV float frcp_(float x){ return 1.f/x; }
#endif
#if __has_builtin(__builtin_amdgcn_exp2f)
DEV float fexp2_(float x){ return __builtin_amdgcn_exp2f(x); }
#else
DEV float fexp2_(float x){ return exp2f(x); }
#endif

DEV float tanh_(float x){
  x = fminf(x, 30.f);
  float e = fexp2_(2.8853900817779268f*x);
  return (e-1.f)*frcp_(e+1.f);
}

// branchless f32 -> OCP e4m3fn (fallback when no HW cvt)
DEV unsigned char f2e4m3(float x){
  unsigned int u = __float_as_uint(x);
  unsigned int s = (u>>24)&0x80u;
  unsigned int mag = u & 0x7fffffffu;
  if (mag > 0x43E00000u) mag = 0x43E00000u;
  mag += 0x000FFFFFu + ((mag>>20)&1u);
  int e = (int)(mag>>23) - 120;
  unsigned int m = (mag>>20)&7u;
  unsigned int r = (e<=0) ? 0u : (((unsigned)e<<3)|m);
  return (unsigned char)(s|r);
}

DEV f32x4 mfma_bf16(s16x8 a, s16x8 b, f32x4 c){
  return __builtin_amdgcn_mfma_f32_16x16x32_bf16(a,b,c,0,0,0);
}
DEV f32x4 mfma_fp8(long a, long b, f32x4 c){
  return __builtin_amdgcn_mfma_f32_16x16x32_fp8_fp8(a,b,c,0,0,0);
}

// LDS-only barrier (no vmcnt drain)
DEV void lds_barrier(){
  asm volatile("s_waitcnt lgkmcnt(0)\n\ts_barrier" ::: "memory");
}

// ---------- sync primitives ----------
// Producers: RELAXED agent-scope atomic stores (write-through to mall) +
// vmcnt(0) drain + relaxed flag. scan1 uses the DEFERRED per-step publish:
// drain step t-1's stores at the top of step t (latency covered by compute).
// Consumers: plain coalesced loads after flag (first-touch, exclusive line
// ranges, written once). Acquire fences only in the classifier tail (y1/y2
// overlay xg1 whose lines scan1 cached).
DEV unsigned aload_rlx(unsigned* p){
  return __hip_atomic_load(p, __ATOMIC_RELAXED, __HIP_MEMORY_SCOPE_AGENT);
}
DEV void astore_rlx(unsigned* p, unsigned v){
  __hip_atomic_store(p, v, __ATOMIC_RELAXED, __HIP_MEMORY_SCOPE_AGENT);
}
DEV void aadd_rlx(unsigned* p, unsigned v){
  __hip_atomic_fetch_add(p, v, __ATOMIC_RELAXED, __HIP_MEMORY_SCOPE_AGENT);
}
DEV void acq_fence(){ __builtin_amdgcn_fence(__ATOMIC_ACQUIRE, "agent"); }
DEV void spin_rlx(unsigned* p, unsigned tgt){
  while (aload_rlx(p) < tgt) __builtin_amdgcn_s_sleep(2);
  asm volatile("" ::: "memory");
}
DEV void block_wait(unsigned* p, unsigned tgt){
  if (threadIdx.x == 0) spin_rlx(p, tgt);
  __syncthreads();
}
DEV void block_wait_acq(unsigned* p, unsigned tgt){
  if (threadIdx.x == 0){ spin_rlx(p, tgt); acq_fence(); }
  __syncthreads();
}
DEV void astore64(unsigned short* p, s16x4 v){
  union { s16x4 s; unsigned long long u; } c; c.s = v;
  __hip_atomic_store((unsigned long long*)(void*)p, c.u,
      __ATOMIC_RELAXED, __HIP_MEMORY_SCOPE_AGENT);
}
DEV void astoref(float* p, float v){
  __hip_atomic_store(p, v, __ATOMIC_RELAXED, __HIP_MEMORY_SCOPE_AGENT);
}
DEV void astore16(unsigned short* p, unsigned short v){
  __hip_atomic_store(p, v, __ATOMIC_RELAXED, __HIP_MEMORY_SCOPE_AGENT);
}
DEV void vm_drain(){ asm volatile("s_waitcnt vmcnt(0)" ::: "memory"); }
DEV void ntf(float* p, float v){ __builtin_nontemporal_store(v, p); }

// ---------- problem constants ----------
#define Bx 128
#define Vx 64
#define Sx 40
#define Dx 256
#define Hx 256
#define NVOC 20001

// d_out element offsets (f32)
#define OFF_OG   0
#define OFF_FAKE 256
#define OFF_DECV 512
#define OFF_GENV 2097664
#define OFF_STS  4194816
#define OFF_LBL  4203008

// bf16 weight-pool element offsets
#define PW_IH  0
#define PW_HH  262144
#define PW_HK  524288
#define PW_1   589824
#define PC_1   622592
#define PC_2   884736
#define PC_O   1409024
#define P_TOT  1410048

#define HPB 264      // scan LDS fp8 row pitch (bytes)
#define BFP 272      // scan h1b LDS pitch (shorts)
#define WHP 272      // worker wh/barv LDS pitch (shorts)

// flag slots (ints): one per 128-B line
#define FCT(t)  ((t)*32)
#define FXG(t)  (2048 + (t)*32)
#define FUC     4096
#define XDONE   4224
#define Y1D     4352
#define Y2D     4480
#define FTOT    8192

// ---------- PRE: embed (direct f32 gather) + weight cvt + flags/passthrough ----------
__global__ void k_pre(const int* __restrict__ seqs, const float* __restrict__ emb,
                      unsigned short* __restrict__ v16,
                      float* __restrict__ decv, float* __restrict__ genv,
                      const float* __restrict__ W_ih, const float* __restrict__ Whh,
                      const float* __restrict__ Whk, const float* __restrict__ W1,
                      const float* __restrict__ C1W, const float* __restrict__ C2W,
                      const float* __restrict__ CoW,
                      unsigned short* __restrict__ pool, unsigned char* __restrict__ whh8,
                      const float* __restrict__ sts, const int* __restrict__ label,
                      float* __restrict__ out, unsigned* __restrict__ flags){
  int bx = blockIdx.x, tid = threadIdx.x;
  if (bx < 8192){                       // embed: v = sum_s relu(emb[idx]) (f32 table, L3-hit)
    int bt = bx, d = tid;
    const int* sp = seqs + (size_t)bt*Sx;
    float acc = 0.f;
    #pragma unroll 8
    for (int s=0;s<Sx;s++) acc += fmaxf(emb[(size_t)sp[s]*Dx + d], 0.f);
    size_t o = (size_t)bt*Dx + d;
    v16[o] = f2bf(acc);
    if ((bt & 63) == 0){ decv[o] = acc; genv[o] = acc; }
    return;
  }
  if (bx < 14724){                      // weight conversions
    int i = (bx-8192)*256 + tid;
    if (i < P_TOT){
      float v;
      if      (i < PW_HH) v = W_ih[i - PW_IH];
      else if (i < PW_HK) v = Whh [i - PW_HH];
      else if (i < PW_1 ) v = Whk [i - PW_HK];
      else if (i < PC_1 ) v = W1  [i - PW_1 ];
      else if (i < PC_2 ) v = C1W [i - PC_1 ];
      else if (i < PC_O ) v = C2W [i - PC_2 ];
      else                v = CoW [i - PC_O ];
      pool[i] = f2bf(v);
    } else if (i < P_TOT + 262144){
      whh8[i - P_TOT] = f2e4m3(16.f*Whh[i - P_TOT]);
    }
    return;
  }
  // misc block: flags init + passthrough outputs
  for (int i=tid;i<FTOT;i+=256) flags[i] = 0u;
  for (int i=tid;i<Bx*Vx;i+=256) out[OFF_STS + i] = sts[i];
  if (tid < Bx) out[OFF_LBL + tid] = (float)label[tid];
}

// ---------- generic MFMA GEMM (xg1) ----------
template<int MODE_A, int MODE_C, int RELU>
__global__ void k_gemm(const unsigned short* __restrict__ A, const unsigned short* __restrict__ Bw,
                       const float* __restrict__ bias1, const float* __restrict__ bias2,
                       unsigned short* __restrict__ C, int K, int Ntot, float scale){
  int tid = threadIdx.x, w = tid>>6, l = tid&63, lm = l&15, q = l>>4;
  int m0 = blockIdx.x*64;
  int n0 = blockIdx.y*256 + w*64;
  f32x4 acc[4][4];
  #pragma unroll
  for (int nt=0;nt<4;nt++){
    int n = n0 + nt*16 + lm;
    float bz = bias1 ? bias1[n] : 0.f;
    if (bias2) bz += bias2[n];
    #pragma unroll
    for (int mt=0;mt<4;mt++) acc[mt][nt] = (f32x4){bz,bz,bz,bz};
  }
  const s16x8* Arow[4];
  #pragma unroll
  for (int mt=0;mt<4;mt++){
    int m = m0 + mt*16 + lm;
    size_t off = (MODE_A==0) ? (size_t)m*K : ((size_t)(m&127)*Vx + (m>>7))*(size_t)K;
    Arow[mt] = (const s16x8*)(A + off);
  }
  int kkn = K/32;
  for (int kk=0; kk<kkn; kk++){
    s16x8 bfr[4];
    #pragma unroll
    for (int nt=0;nt<4;nt++){
      int n = n0 + nt*16 + lm;
      bfr[nt] = *(const s16x8*)(Bw + (size_t)n*K + kk*32 + q*8);
    }
    #pragma unroll
    for (int mt=0;mt<4;mt++){
      s16x8 afr = Arow[mt][kk*4 + q];
      #pragma unroll
      for (int nt=0;nt<4;nt++)
        acc[mt][nt] = mfma_bf16(afr, bfr[nt], acc[mt][nt]);
    }
  }
  #pragma unroll
  for (int mt=0;mt<4;mt++){
    int mbase = m0 + mt*16 + q*4;
    #pragma unroll
    for (int nt=0;nt<4;nt++){
      int n = n0 + nt*16 + lm;
      if (MODE_C==0){
        #pragma unroll
        for (int r=0;r<4;r++){
          float val = scale*acc[mt][nt][r];
          if (RELU) val = fmaxf(val, 0.f);
          C[(size_t)(mbase+r)*Ntot + n] = f2bf(val);
        }
      } else {
        int tt = mbase>>7, bb = mbase&127;
        int gg = bb>>4;
        s16x4 sv;
        #pragma unroll
        for (int r=0;r<4;r++) sv[r] = (short)f2bf(scale*acc[mt][nt][r]);
        *(s16x4*)(C + (((size_t)tt*8 + gg)*1024 + n)*16 + (bb&15)) = sv;
      }
    }
  }
}

// ---------- LSTM gate activations (inputs scaled by 256) ----------
DEV void lstm_act(const f32x4* A, float* cst, float* hv){
  const float K1 = 1.4426950408889634f/256.f;
  #pragma unroll
  for (int r=0;r<4;r++){
    float iv = frcp_(1.f + fexp2_(-K1*A[0][r]));
    float fv = frcp_(1.f + fexp2_(-K1*A[1][r]));
    float eg = fexp2_(2.f*K1*A[2][r]);
    float gv = (eg-1.f)*frcp_(eg+1.f);
    float ov = frcp_(1.f + fexp2_(-K1*A[3][r]));
    float cv = fv*cst[r] + iv*gv;
    cst[r] = cv;
    float ec = fexp2_(2.8853900817779268f*fminf(cv,30.f));
    hv[r] = ov*(ec-1.f)*frcp_(ec+1.f);
  }
}

// store 4 h values (rows q*4+r) as fp8(16*h) at column j of next h-buffer
DEV void store_h_fp8(unsigned char* hn, int q, const float* hv){
#if __has_builtin(__builtin_amdgcn_cvt_pk_fp8_f32)
  int p01 = __builtin_amdgcn_cvt_pk_fp8_f32(16.f*hv[0], 16.f*hv[1], 0, false);
  int p23 = __builtin_amdgcn_cvt_pk_fp8_f32(16.f*hv[2], 16.f*hv[3], 0, false);
  hn[(q*4+0)*HPB] = (unsigned char)p01;
  hn[(q*4+1)*HPB] = (unsigned char)(p01>>8);
  hn[(q*4+2)*HPB] = (unsigned char)p23;
  hn[(q*4+3)*HPB] = (unsigned char)(p23>>8);
#else
  #pragma unroll
  for (int r=0;r<4;r++) hn[(q*4+r)*HPB] = f2e4m3(16.f*hv[r]);
#endif
}

// ---------- scan1: plain xg1 reads; DEFERRED per-step publish (R4-proven) ----------
DEV void scan1_body(unsigned char* smem, const unsigned char* __restrict__ W8,
                    const unsigned short* __restrict__ xg1, unsigned short* __restrict__ hist,
                    int g, unsigned* __restrict__ flags){
  unsigned char*  hl  = smem;                               // 2*16*264 fp8 dbuf
  unsigned short* h1b = (unsigned short*)(smem + 8448);     // [16][272] bf16
  int tid = threadIdx.x;
  int w = tid>>6, l = tid&63, lm = l&15, q = l>>4;
  int j = w*16 + lm;
  for (int i=tid;i<8448;i+=1024) hl[i] = 0;
  long Bf[4][8];
  #pragma unroll
  for (int qq=0;qq<4;qq++){
    int n = qq*256 + j;
    #pragma unroll
    for (int kk=0;kk<8;kk++)
      Bf[qq][kk] = *(const long*)(W8 + (size_t)n*256 + kk*32 + q*8);
  }
  float cst[4] = {0.f,0.f,0.f,0.f};
  const unsigned short* xgb = xg1 + (size_t)g*16384 + q*4;
  s16x4 xc[4], xn[4];
  #pragma unroll
  for (int qq=0;qq<4;qq++) xc[qq] = *(const s16x4*)(xgb + (qq*256+j)*16);
  __syncthreads();
  const unsigned char* hrd = hl + lm*HPB + q*8;
  #pragma unroll 1
  for (int t=0;t<Vx;t++){
    if (t > 0){
      vm_drain();                       // step t-1 stores drained (covered by compute)
      __syncthreads();
      if (tid == 0) aadd_rlx(&flags[FCT(t-1)], 1);   // deferred publish
    }
    if (t < Vx-1){
      #pragma unroll
      for (int qq=0;qq<4;qq++)
        xn[qq] = *(const s16x4*)(xgb + (size_t)(t+1)*131072 + (qq*256+j)*16);
    }
    const unsigned char* hb = hrd + (t&1)*4224;
    f32x4 A[4];
    #pragma unroll
    for (int qq=0;qq<4;qq++){
      #pragma unroll
      for (int r=0;r<4;r++) A[qq][r] = bf2f((unsigned short)xc[qq][r]);
    }
    #pragma unroll
    for (int kk=0;kk<8;kk++){
      long af = *(const long*)(hb + kk*32);
      A[0] = mfma_fp8(af, Bf[0][kk], A[0]);
      A[1] = mfma_fp8(af, Bf[1][kk], A[1]);
      A[2] = mfma_fp8(af, Bf[2][kk], A[2]);
      A[3] = mfma_fp8(af, Bf[3][kk], A[3]);
    }
    float hv[4];
    lstm_act(A, cst, hv);
    store_h_fp8(hl + ((t+1)&1)*4224 + j, q, hv);
    #pragma unroll
    for (int r=0;r<4;r++) h1b[(q*4+r)*BFP + j] = f2bf(hv[r]);
    lds_barrier();
    {
      int row = tid>>6, c4 = (tid&63)*4;
      s16x4 hx = *(const s16x4*)(h1b + row*BFP + c4);
      astore64(hist + ((size_t)t*Bx + g*16 + row)*Hx + c4, hx);   // issued, drained next step
    }
    #pragma unroll
    for (int qq=0;qq<4;qq++) xc[qq] = xn[qq];
  }
  vm_drain();
  __syncthreads();
  if (tid == 0){ aadd_rlx(&flags[FCT(63)], 1); aadd_rlx(&flags[XDONE], 1); }
}

// ---------- scan2: plain xg2 reads (first-touch), 2-deep lookahead ----------
DEV void scan2_body(unsigned char* smem, const unsigned char* __restrict__ W8,
                    const unsigned short* __restrict__ xg2, unsigned short* __restrict__ h2,
                    int g, unsigned* __restrict__ flags){
  unsigned char*  hl  = smem;
  unsigned short* h1b = (unsigned short*)(smem + 8448);
  int tid = threadIdx.x;
  int w = tid>>6, l = tid&63, lm = l&15, q = l>>4;
  int j = w*16 + lm;
  for (int i=tid;i<8448;i+=1024) hl[i] = 0;
  long Bf[4][8];
  #pragma unroll
  for (int qq=0;qq<4;qq++){
    int n = qq*256 + j;
    #pragma unroll
    for (int kk=0;kk<8;kk++)
      Bf[qq][kk] = *(const long*)(W8 + (size_t)n*256 + kk*32 + q*8);
  }
  float cst[4] = {0.f,0.f,0.f,0.f};
  const unsigned short* xgb = xg2 + (size_t)g*16384 + q*4;
  s16x4 xc[4], xn1[4], xn2[4];
  block_wait(&flags[FXG(0)], 1);
  #pragma unroll
  for (int qq=0;qq<4;qq++) xc[qq] = *(const s16x4*)(xgb + (qq*256+j)*16);
  block_wait(&flags[FXG(1)], 1);
  #pragma unroll
  for (int qq=0;qq<4;qq++) xn1[qq] = *(const s16x4*)(xgb + 131072 + (qq*256+j)*16);
  int skip = 0;
  const unsigned char* hrd = hl + lm*HPB + q*8;
  #pragma unroll 1
  for (int t=0;t<Vx;t++){
    if (t+2 < Vx){
      if (tid == 0){
        if (!skip) spin_rlx(&flags[FXG(t+2)], 1);
        skip = (t+3 < Vx) && (aload_rlx(&flags[FXG(t+3)]) >= 1);
      }
      __syncthreads();
      #pragma unroll
      for (int qq=0;qq<4;qq++)
        xn2[qq] = *(const s16x4*)(xgb + (size_t)(t+2)*131072 + (qq*256+j)*16);
    }
    const unsigned char* hb = hrd + (t&1)*4224;
    f32x4 A[4];
    #pragma unroll
    for (int qq=0;qq<4;qq++){
      #pragma unroll
      for (int r=0;r<4;r++) A[qq][r] = bf2f((unsigned short)xc[qq][r]);
    }
    #pragma unroll
    for (int kk=0;kk<8;kk++){
      long af = *(const long*)(hb + kk*32);
      A[0] = mfma_fp8(af, Bf[0][kk], A[0]);
      A[1] = mfma_fp8(af, Bf[1][kk], A[1]);
      A[2] = mfma_fp8(af, Bf[2][kk], A[2]);
      A[3] = mfma_fp8(af, Bf[3][kk], A[3]);
    }
    float hv[4];
    lstm_act(A, cst, hv);
    store_h_fp8(hl + ((t+1)&1)*4224 + j, q, hv);
    if (t == Vx-1){
      #pragma unroll
      for (int r=0;r<4;r++) h1b[(q*4+r)*BFP + j] = f2bf(hv[r]);
      lds_barrier();
      {
        int row = tid>>6, c4 = (tid&63)*4;
        s16x4 hx = *(const s16x4*)(h1b + row*BFP + c4);
        astore64(h2 + (size_t)(g*16 + row)*Hx + c4, hx);
      }
      vm_drain();
      __syncthreads();
      if (tid == 0) aadd_rlx(&flags[XDONE], 1);
    } else {
      lds_barrier();
    }
    #pragma unroll
    for (int qq=0;qq<4;qq++){ xc[qq] = xn1[qq]; xn1[qq] = xn2[qq]; }
  }
}

// xg2 tile GEMM for step `tile`: A rows from LDS (barv) or global v16 (e_k)
template<int ALDS>
DEV void xg2_tile(const unsigned short* Ab, const unsigned short* __restrict__ pool,
                  const float* __restrict__ b_ih, const float* __restrict__ b_hh,
                  unsigned short* __restrict__ xg2, int tile, int w, int lm, int q){
  int mh = (w&1)*64, nb = (w>>1)*128;
  #pragma unroll 1
  for (int sc=0; sc<4; sc++){
    int n0 = nb + sc*32;
    f32x4 acc[4][2];
    #pragma unroll
    for (int nt=0;nt<2;nt++){
      int n = n0 + nt*16 + lm;
      float bz = b_ih[n] + b_hh[n];
      #pragma unroll
      for (int mt=0;mt<4;mt++) acc[mt][nt] = (f32x4){bz,bz,bz,bz};
    }
    #pragma unroll
    for (int kk=0;kk<8;kk++){
      s16x8 bfr[2];
      #pragma unroll
      for (int nt=0;nt<2;nt++){
        int n = n0 + nt*16 + lm;
        bfr[nt] = *(const s16x8*)(pool + PW_IH + (size_t)n*256 + kk*32 + q*8);
      }
      #pragma unroll
      for (int mt=0;mt<4;mt++){
        int row = mh + mt*16 + lm;
        s16x8 afr = ALDS ? *(const s16x8*)(Ab + (size_t)row*WHP + kk*32 + q*8)
                         : *(const s16x8*)(Ab + (size_t)row*Vx*Dx + kk*32 + q*8);
        acc[mt][0] = mfma_bf16(afr, bfr[0], acc[mt][0]);
        acc[mt][1] = mfma_bf16(afr, bfr[1], acc[mt][1]);
      }
    }
    #pragma unroll
    for (int mt=0;mt<4;mt++){
      int m = mh + mt*16 + q*4;
      int gg = m>>4;
      #pragma unroll
      for (int nt=0;nt<2;nt++){
        int n = n0 + nt*16 + lm;
        s16x4 sv;
        #pragma unroll
        for (int r=0;r<4;r++) sv[r] = (short)f2bf(256.f*acc[mt][nt][r]);
        astore64(xg2 + (((size_t)tile*8 + gg)*1024 + n)*16 + (m&15), sv);
      }
    }
  }
}

// ---------- fused worker: wh -> attn -> barv(LDS) -> xg2[t+1] ----------
DEV void worker_body(unsigned short* whs, int t,
    const unsigned short* __restrict__ hist1, const unsigned short* __restrict__ v16,
    const float* __restrict__ u, const unsigned short* __restrict__ pool,
    const float* __restrict__ bhk, const float* __restrict__ W2, const float* __restrict__ b2,
    const float* __restrict__ b_ih, const float* __restrict__ b_hh,
    float* __restrict__ decv, float* __restrict__ genv,
    unsigned short* __restrict__ xg2, unsigned* __restrict__ flags){
  int tid = threadIdx.x, w = tid>>6, l = tid&63, lm = l&15, q = l>>4;
  if (t == 63){
    // xg2[0] from e_k (= v16[:,0,:]) directly; no waits (v16 from prior kernel)
    xg2_tile<0>(v16, pool, b_ih, b_hh, xg2, 0, w, lm, q);
    vm_drain();
    __syncthreads();
    if (tid == 0) astore_rlx(&flags[FXG(0)], 1);
    return;
  }
  block_wait(&flags[FCT(t)], 8);                // scan1 published h[t]
  {
    int r0 = (w&7)*16, n0 = (w>>3)*128;
    const unsigned short* Ar = hist1 + ((size_t)t*Bx + r0 + lm)*Hx;
    f32x4 acc[8];
    #pragma unroll
    for (int nt=0;nt<8;nt++){
      float bz = bhk[n0 + nt*16 + lm];
      acc[nt] = (f32x4){bz,bz,bz,bz};
    }
    #pragma unroll
    for (int kk=0;kk<8;kk++){
      s16x8 afr = *(const s16x8*)(Ar + kk*32 + q*8);   // plain, first-touch
      #pragma unroll
      for (int nt=0;nt<8;nt++){
        int n = n0 + nt*16 + lm;
        s16x8 bfr = *(const s16x8*)(pool + PW_HK + (size_t)n*256 + kk*32 + q*8);
        acc[nt] = mfma_bf16(afr, bfr, acc[nt]);
      }
    }
    #pragma unroll
    for (int nt=0;nt<8;nt++){
      int n = n0 + nt*16 + lm, mb = r0 + q*4;
      #pragma unroll
      for (int r=0;r<4;r++) whs[(size_t)(mb+r)*WHP + n] = f2bf(acc[nt][r]);
    }
  }
  if (tid == 0) spin_rlx(&flags[FUC], 8);
  __syncthreads();                              // + orders whs stores
  if (w < 8){
    int m0l = w*16;
    f32x4 a2[4];
    #pragma unroll
    for (int nt=0;nt<4;nt++){
      int n = nt*16 + lm;
      #pragma unroll
      for (int r=0;r<4;r++) a2[nt][r] = u[(size_t)(m0l + q*4 + r)*64 + n];
    }
    #pragma unroll
    for (int kk=0;kk<8;kk++){
      s16x8 afr = *(const s16x8*)(whs + (size_t)(m0l+lm)*WHP + kk*32 + q*8);
      #pragma unroll
      for (int nt=0;nt<4;nt++){
        int n = nt*16 + lm;
        s16x8 bfr = *(const s16x8*)(pool + PW_1 + (size_t)n*512 + 256 + kk*32 + q*8);
        a2[nt] = mfma_bf16(afr, bfr, a2[nt]);
      }
    }
    float p0a[4] = {0,0,0,0}, p1a[4] = {0,0,0,0};
    #pragma unroll
    for (int nt=0;nt<4;nt++){
      int n = nt*16 + lm;
      float w2a = W2[n], w2b = W2[64+n];
      #pragma unroll
      for (int r=0;r<4;r++){
        float z = tanh_(a2[nt][r]);
        p0a[r] += z*w2a; p1a[r] += z*w2b;
      }
    }
    #pragma unroll
    for (int s=1;s<16;s<<=1){
      #pragma unroll
      for (int r=0;r<4;r++){ p0a[r] += __shfl_xor(p0a[r], s, 16); p1a[r] += __shfl_xor(p1a[r], s, 16); }
    }
    float bb0 = b2[0], bb1 = b2[1];
    int d0 = lm*16;
    #pragma unroll
    for (int r=0;r<4;r++){
      int b = m0l + q*4 + r;
      float g0 = p0a[r]+bb0, g1 = p1a[r]+bb1;
      float al0 = frcp_(1.f + fexp2_(1.4426950408889634f*(g1-g0)));
      float al1 = 1.f - al0;
      const unsigned short* ek = v16 + (size_t)b*Vx*Dx + d0;
      unsigned short* whp = whs + (size_t)b*WHP + d0;
      size_t ob = ((size_t)b*Vx + (t+1))*Dx + d0;
      #pragma unroll
      for (int c=0;c<2;c++){
        s16x8 e8 = *(const s16x8*)(ek + c*8);
        s16x8 w8 = *(const s16x8*)(whp + c*8);
        s16x8 o16;
        #pragma unroll
        for (int jj=0;jj<8;jj++){
          float o = al0*bf2f((unsigned short)e8[jj]) + al1*bf2f((unsigned short)w8[jj]);
          ntf(decv + ob + c*8 + jj, o);
          ntf(genv + ob + c*8 + jj, o);
          o16[jj] = (short)f2bf(o);
        }
        *(s16x8*)(whp + c*8) = o16;             // barv[t+1] in place
      }
    }
  }
  __syncthreads();                              // barv visible to all waves
  xg2_tile<1>(whs, pool, b_ih, b_hh, xg2, t+1, w, lm, q);
  vm_drain();
  __syncthreads();
  if (tid == 0) astore_rlx(&flags[FXG(t+1)], 1);
}

// ---------- classifier GEMM (tid<256 active; plain A reads post-acquire) ----------
DEV void cls_gemm(const unsigned short* __restrict__ A, const unsigned short* __restrict__ Bw,
                  const float* __restrict__ bias, unsigned short* __restrict__ C,
                  int K, int Ntot, int bxx, int byy){
  int tid = threadIdx.x, w = tid>>6, l = tid&63, lm = l&15, q = l>>4;
  int m0 = bxx*64, n0 = byy*256 + w*64;
  f32x4 acc[4][4];
  #pragma unroll
  for (int nt=0;nt<4;nt++){
    int n = n0 + nt*16 + lm;
    float bz = bias[n];
    #pragma unroll
    for (int mt=0;mt<4;mt++) acc[mt][nt] = (f32x4){bz,bz,bz,bz};
  }
  const s16x8* Arow[4];
  #pragma unroll
  for (int mt=0;mt<4;mt++)
    Arow[mt] = (const s16x8*)(A + (size_t)(m0 + mt*16 + lm)*K);
  int kkn = K/32;
  for (int kk=0; kk<kkn; kk++){
    s16x8 bfr[4];
    #pragma unroll
    for (int nt=0;nt<4;nt++){
      int n = n0 + nt*16 + lm;
      bfr[nt] = *(const s16x8*)(Bw + (size_t)n*K + kk*32 + q*8);
    }
    #pragma unroll
    for (int mt=0;mt<4;mt++){
      s16x8 afr = Arow[mt][kk*4 + q];
      #pragma unroll
      for (int nt=0;nt<4;nt++)
        acc[mt][nt] = mfma_bf16(afr, bfr[nt], acc[mt][nt]);
    }
  }
  #pragma unroll
  for (int mt=0;mt<4;mt++){
    int mbase = m0 + mt*16 + q*4;
    #pragma unroll
    for (int nt=0;nt<4;nt++){
      int n = n0 + nt*16 + lm;
      #pragma unroll
      for (int r=0;r<4;r++)
        astore16(C + (size_t)(mbase+r)*Ntot + n, f2bf(fmaxf(acc[mt][nt][r], 0.f)));
    }
  }
}

// ---------- MEGA: scan1 || workers || scan2 || u || post ----------
__global__ __launch_bounds__(1024) void k_mega(
    const unsigned char* __restrict__ W8,
    unsigned short* __restrict__ xg1, unsigned short* __restrict__ xg2,
    unsigned short* __restrict__ hist1,
    const unsigned short* __restrict__ v16, float* __restrict__ u,
    const unsigned short* __restrict__ pool,
    const float* __restrict__ bhk, const float* __restrict__ W2, const float* __restrict__ b2,
    const float* __restrict__ b1, const float* __restrict__ b_ih, const float* __restrict__ b_hh,
    const float* __restrict__ C1b, const float* __restrict__ C2b, const float* __restrict__ Cob,
    float* __restrict__ decv, float* __restrict__ genv, float* __restrict__ out,
    unsigned* __restrict__ flags){
  __shared__ __align__(16) unsigned char smem[69632];
  int blk = blockIdx.x;
  unsigned short* X  = hist1 + (size_t)(Vx-1)*Bx*Hx;       // [256][256]: h1[63] ; h2
  unsigned short* h2 = hist1 + (size_t)Vx*Bx*Hx;
  unsigned short* y1 = xg1;                                 // overlays (xg1 dead post-scan1)
  unsigned short* y2 = xg1 + 262144;
  if (blk < 8){
    scan1_body(smem, W8, xg1, hist1, blk, flags);
  } else if (blk < 16){
    scan2_body(smem, W8, xg2, h2, blk-8, flags);
  } else if (blk < 80){
    worker_body((unsigned short*)smem, blk-16, hist1, v16, u, pool, bhk, W2, b2,
                b_ih, b_hh, decv, genv, xg2, flags);
  } else if (blk < 88){
    // u GEMV: 8 blocks x 1024 threads = 8192 = 128 b x 64 n
    int t2 = (blk-80)*1024 + threadIdx.x;
    int b = t2>>6, n = t2&63;
    const s16x8* vr = (const s16x8*)(v16 + (size_t)b*Vx*Dx);
    const s16x8* wr = (const s16x8*)(pool + PW_1 + (size_t)n*512);
    float a = b1[n];
    for (int kk=0;kk<32;kk++){
      s16x8 x = vr[kk], ww = wr[kk];
      #pragma unroll
      for (int jj=0;jj<8;jj++) a += bf2f((unsigned short)x[jj])*bf2f((unsigned short)ww[jj]);
    }
    astoref(u + t2, a);
    vm_drain();
    __syncthreads();
    if (threadIdx.x == 0) aadd_rlx(&flags[FUC], 1);
  } else if (blk < 104){
    block_wait_acq(&flags[XDONE], 16);
    int p = blk-88;
    if (threadIdx.x < 256) cls_gemm(X, pool+PC_1, C1b, y1, 256, 1024, p&3, p>>2);
    vm_drain();
    __syncthreads();
    if (threadIdx.x == 0) aadd_rlx(&flags[Y1D], 1);
  } else if (blk < 112){
    block_wait_acq(&flags[Y1D], 16);
    int p = blk-104;
    if (threadIdx.x < 256) cls_gemm(y1, pool+PC_2, C2b, y2, 1024, 512, p&3, p>>2);
    vm_drain();
    __syncthreads();
    if (threadIdx.x == 0) aadd_rlx(&flags[Y2D], 1);
  } else {
    block_wait_acq(&flags[Y2D], 8);
    if (threadIdx.x < 256){
      int t2 = (blk-112)*256 + threadIdx.x;
      int m = t2>>1, n = t2&1;
      const s16x8* yr = (const s16x8*)(y2 + (size_t)m*512);
      const s16x8* wr = (const s16x8*)(pool + PC_O + (size_t)n*512);
      float a = Cob[n];
      for (int kk=0;kk<64;kk++){
        s16x8 yv = yr[kk], ww = wr[kk];
        #pragma unroll
        for (int jj=0;jj<8;jj++) a += bf2f((unsigned short)yv[jj])*bf2f((unsigned short)ww[jj]);
      }
      int base = (m < 128) ? (OFF_OG + m*2) : (OFF_FAKE + (m-128)*2);
      out[base + n] = a;
    }
  }
}

// ---------- launch ----------
extern "C" void kernel_launch(void* const* d_in, const int* in_sizes, int n_in,
                              void* d_out, int out_size, void* d_ws, size_t ws_size,
                              hipStream_t stream) {
  const int*   seqs  = (const int*)d_in[0];
  const float* sts   = (const float*)d_in[3];
  const int*   label = (const int*)d_in[5];
  const float* emb   = (const float*)d_in[6];
  const float* W_ih  = (const float*)d_in[7];
  const float* W_hh  = (const float*)d_in[8];
  const float* b_ih  = (const float*)d_in[9];
  const float* b_hh  = (const float*)d_in[10];
  const float* Whk   = (const float*)d_in[11];
  const float* bhk   = (const float*)d_in[12];
  const float* W1    = (const float*)d_in[13];
  const float* b1    = (const float*)d_in[14];
  const float* W2    = (const float*)d_in[15];
  const float* b2    = (const float*)d_in[16];
  const float* C1b   = (const float*)d_in[18];
  const float* C2b   = (const float*)d_in[20];
  const float* Cob   = (const float*)d_in[22];
  float* out = (float*)d_out;

  char* ws = (char*)d_ws;
  unsigned short* v16    = (unsigned short*)(ws + 0);            //  4 MiB [b][t][d] bf16
  unsigned short* xg1    = (unsigned short*)(ws + (4<<20));      // 16 MiB [t][g][n][16]
  unsigned short* hist1  = (unsigned short*)(ws + (20<<20));     //  4 MiB [t][b][j] + 64K h2
  unsigned short* xg2    = (unsigned short*)(ws + (25<<20));     // 16 MiB [t][g][n][16]
  float*          u      = (float*)(ws + (41<<20));              // 32 KiB
  unsigned char*  whh8   = (unsigned char*)(ws + (41<<20) + (64<<10));   // 256 KiB
  unsigned*       flags  = (unsigned*)(ws + (41<<20) + (384<<10));       // 32 KiB
  unsigned short* pool   = (unsigned short*)(ws + (42<<20));     // 2.82 MiB

  float* decv = out + OFF_DECV;
  float* genv = out + OFF_GENV;

  k_pre<<<dim3(14725), dim3(256), 0, stream>>>(seqs, emb, v16, decv, genv,
      W_ih, W_hh, Whk, W1, (const float*)d_in[17], (const float*)d_in[19],
      (const float*)d_in[21], pool, whh8, sts, label, out, flags);
  k_gemm<1,1,0><<<dim3(128,4), dim3(256), 0, stream>>>(v16, pool+PW_IH, b_ih, b_hh, xg1, 256, 1024, 256.f);
  k_mega<<<dim3(114), dim3(1024), 0, stream>>>(whh8, xg1, xg2, hist1, v16, u, pool,
      bhk, W2, b2, b1, b_ih, b_hh, C1b, C2b, Cob, decv, genv, out, flags);
}

// Round 10
// 493.858 us; speedup vs baseline: 1.0415x; 1.0415x over previous
//
#include <hip/hip_runtime.h>

#define DEV __device__ __forceinline__

typedef float f32x4 __attribute__((ext_vector_type(4)));
typedef short s16x8 __attribute__((ext_vector_type(8)));
typedef short s16x4 __attribute__((ext_vector_type(4)));

// ---------- scalar helpers ----------
DEV unsigned short f2bf(float f){
  unsigned int u = __float_as_uint(f);
  u += 0x7fffu + ((u>>16)&1u);
  return (unsigned short)(u>>16);
}
DEV float bf2f(unsigned short h){ return __uint_as_float(((unsigned int)h)<<16); }

#if __has_builtin(__builtin_amdgcn_rcpf)
DEV float frcp_(float x){ return __builtin_amdgcn_rcpf(x); }
#else
DEV float frcp_(float x){ return 1.f/x; }
#endif
#if __has_builtin(__builtin_amdgcn_exp2f)
DEV float fexp2_(float x){ return __builtin_amdgcn_exp2f(x); }
#else
DEV float fexp2_(float x){ return exp2f(x); }
#endif

DEV float tanh_(float x){
  x = fminf(x, 30.f);
  float e = fexp2_(2.8853900817779268f*x);
  return (e-1.f)*frcp_(e+1.f);
}

// branchless f32 -> OCP e4m3fn (fallback when no HW cvt)
DEV unsigned char f2e4m3(float x){
  unsigned int u = __float_as_uint(x);
  unsigned int s = (u>>24)&0x80u;
  unsigned int mag = u & 0x7fffffffu;
  if (mag > 0x43E00000u) mag = 0x43E00000u;
  mag += 0x000FFFFFu + ((mag>>20)&1u);
  int e = (int)(mag>>23) - 120;
  unsigned int m = (mag>>20)&7u;
  unsigned int r = (e<=0) ? 0u : (((unsigned)e<<3)|m);
  return (unsigned char)(s|r);
}

DEV f32x4 mfma_bf16(s16x8 a, s16x8 b, f32x4 c){
  return __builtin_amdgcn_mfma_f32_16x16x32_bf16(a,b,c,0,0,0);
}
DEV f32x4 mfma_fp8(long a, long b, f32x4 c){
  return __builtin_amdgcn_mfma_f32_16x16x32_fp8_fp8(a,b,c,0,0,0);
}

// LDS-only barrier (no vmcnt drain)
DEV void lds_barrier(){
  asm volatile("s_waitcnt lgkmcnt(0)\n\ts_barrier" ::: "memory");
}

// ---------- sync primitives ----------
// Producers: RELAXED agent-scope atomic stores (write-through to mall) +
// vmcnt(0) drain + relaxed flag (scan1: immediate per-step, R4-proven).
// Consumers: plain coalesced loads after flag (first-touch, exclusive line
// ranges, written once). Poll rates are TIERED: per-step flags (FCT/FXG)
// spin fast (s_sleep 2, spread over 64 lines); phase-boundary flags
// (XDONE/Y1D/Y2D: many blocks on ONE line) spin slow (s_sleep 64) to avoid
// saturating the mall slice that serves the flags region. Acquire fences
// only in the classifier tail (y1/y2 overlay xg1 whose lines scan1 cached).
DEV unsigned aload_rlx(unsigned* p){
  return __hip_atomic_load(p, __ATOMIC_RELAXED, __HIP_MEMORY_SCOPE_AGENT);
}
DEV void astore_rlx(unsigned* p, unsigned v){
  __hip_atomic_store(p, v, __ATOMIC_RELAXED, __HIP_MEMORY_SCOPE_AGENT);
}
DEV void aadd_rlx(unsigned* p, unsigned v){
  __hip_atomic_fetch_add(p, v, __ATOMIC_RELAXED, __HIP_MEMORY_SCOPE_AGENT);
}
DEV void acq_fence(){ __builtin_amdgcn_fence(__ATOMIC_ACQUIRE, "agent"); }
DEV void spin_rlx(unsigned* p, unsigned tgt){
  while (aload_rlx(p) < tgt) __builtin_amdgcn_s_sleep(2);
  asm volatile("" ::: "memory");
}
DEV void spin_med(unsigned* p, unsigned tgt){
  while (aload_rlx(p) < tgt) __builtin_amdgcn_s_sleep(16);
  asm volatile("" ::: "memory");
}
DEV void spin_slow(unsigned* p, unsigned tgt){
  while (aload_rlx(p) < tgt) __builtin_amdgcn_s_sleep(64);
  asm volatile("" ::: "memory");
}
DEV void block_wait(unsigned* p, unsigned tgt){
  if (threadIdx.x == 0) spin_rlx(p, tgt);
  __syncthreads();
}
DEV void block_wait_acq_slow(unsigned* p, unsigned tgt){
  if (threadIdx.x == 0){ spin_slow(p, tgt); acq_fence(); }
  __syncthreads();
}
DEV void astore64(unsigned short* p, s16x4 v){
  union { s16x4 s; unsigned long long u; } c; c.s = v;
  __hip_atomic_store((unsigned long long*)(void*)p, c.u,
      __ATOMIC_RELAXED, __HIP_MEMORY_SCOPE_AGENT);
}
DEV void astoref(float* p, float v){
  __hip_atomic_store(p, v, __ATOMIC_RELAXED, __HIP_MEMORY_SCOPE_AGENT);
}
DEV void astore16(unsigned short* p, unsigned short v){
  __hip_atomic_store(p, v, __ATOMIC_RELAXED, __HIP_MEMORY_SCOPE_AGENT);
}
DEV void vm_drain(){ asm volatile("s_waitcnt vmcnt(0)" ::: "memory"); }
DEV void ntf(float* p, float v){ __builtin_nontemporal_store(v, p); }

// ---------- problem constants ----------
#define Bx 128
#define Vx 64
#define Sx 40
#define Dx 256
#define Hx 256
#define NVOC 20001

// d_out element offsets (f32)
#define OFF_OG   0
#define OFF_FAKE 256
#define OFF_DECV 512
#define OFF_GENV 2097664
#define OFF_STS  4194816
#define OFF_LBL  4203008

// bf16 weight-pool element offsets
#define PW_IH  0
#define PW_HH  262144
#define PW_HK  524288
#define PW_1   589824
#define PC_1   622592
#define PC_2   884736
#define PC_O   1409024
#define P_TOT  1410048

#define HPB 264      // scan LDS fp8 row pitch (bytes)
#define BFP 272      // scan h1b LDS pitch (shorts)
#define WHP 272      // worker wh/barv LDS pitch (shorts)

// flag slots (ints): one per 128-B line
#define FCT(t)  ((t)*32)
#define FXG(t)  (2048 + (t)*32)
#define FUC     4096
#define XDONE   4224
#define Y1D     4352
#define Y2D     4480
#define FTOT    8192

// ---------- PRE: embed (direct f32 gather) + weight cvt + flags/passthrough ----------
__global__ void k_pre(const int* __restrict__ seqs, const float* __restrict__ emb,
                      unsigned short* __restrict__ v16,
                      float* __restrict__ decv, float* __restrict__ genv,
                      const float* __restrict__ W_ih, const float* __restrict__ Whh,
                      const float* __restrict__ Whk, const float* __restrict__ W1,
                      const float* __restrict__ C1W, const float* __restrict__ C2W,
                      const float* __restrict__ CoW,
                      unsigned short* __restrict__ pool, unsigned char* __restrict__ whh8,
                      const float* __restrict__ sts, const int* __restrict__ label,
                      float* __restrict__ out, unsigned* __restrict__ flags){
  int bx = blockIdx.x, tid = threadIdx.x;
  if (bx < 8192){                       // embed: v = sum_s relu(emb[idx]) (f32 table, L3-hit)
    int bt = bx, d = tid;
    const int* sp = seqs + (size_t)bt*Sx;
    float acc = 0.f;
    #pragma unroll 8
    for (int s=0;s<Sx;s++) acc += fmaxf(emb[(size_t)sp[s]*Dx + d], 0.f);
    size_t o = (size_t)bt*Dx + d;
    v16[o] = f2bf(acc);
    if ((bt & 63) == 0){ decv[o] = acc; genv[o] = acc; }
    return;
  }
  if (bx < 14724){                      // weight conversions
    int i = (bx-8192)*256 + tid;
    if (i < P_TOT){
      float v;
      if      (i < PW_HH) v = W_ih[i - PW_IH];
      else if (i < PW_HK) v = Whh [i - PW_HH];
      else if (i < PW_1 ) v = Whk [i - PW_HK];
      else if (i < PC_1 ) v = W1  [i - PW_1 ];
      else if (i < PC_2 ) v = C1W [i - PC_1 ];
      else if (i < PC_O ) v = C2W [i - PC_2 ];
      else                v = CoW [i - PC_O ];
      pool[i] = f2bf(v);
    } else if (i < P_TOT + 262144){
      whh8[i - P_TOT] = f2e4m3(16.f*Whh[i - P_TOT]);
    }
    return;
  }
  // misc block: flags init + passthrough outputs
  for (int i=tid;i<FTOT;i+=256) flags[i] = 0u;
  for (int i=tid;i<Bx*Vx;i+=256) out[OFF_STS + i] = sts[i];
  if (tid < Bx) out[OFF_LBL + tid] = (float)label[tid];
}

// ---------- generic MFMA GEMM (xg1) ----------
template<int MODE_A, int MODE_C, int RELU>
__global__ void k_gemm(const unsigned short* __restrict__ A, const unsigned short* __restrict__ Bw,
                       const float* __restrict__ bias1, const float* __restrict__ bias2,
                       unsigned short* __restrict__ C, int K, int Ntot, float scale){
  int tid = threadIdx.x, w = tid>>6, l = tid&63, lm = l&15, q = l>>4;
  int m0 = blockIdx.x*64;
  int n0 = blockIdx.y*256 + w*64;
  f32x4 acc[4][4];
  #pragma unroll
  for (int nt=0;nt<4;nt++){
    int n = n0 + nt*16 + lm;
    float bz = bias1 ? bias1[n] : 0.f;
    if (bias2) bz += bias2[n];
    #pragma unroll
    for (int mt=0;mt<4;mt++) acc[mt][nt] = (f32x4){bz,bz,bz,bz};
  }
  const s16x8* Arow[4];
  #pragma unroll
  for (int mt=0;mt<4;mt++){
    int m = m0 + mt*16 + lm;
    size_t off = (MODE_A==0) ? (size_t)m*K : ((size_t)(m&127)*Vx + (m>>7))*(size_t)K;
    Arow[mt] = (const s16x8*)(A + off);
  }
  int kkn = K/32;
  for (int kk=0; kk<kkn; kk++){
    s16x8 bfr[4];
    #pragma unroll
    for (int nt=0;nt<4;nt++){
      int n = n0 + nt*16 + lm;
      bfr[nt] = *(const s16x8*)(Bw + (size_t)n*K + kk*32 + q*8);
    }
    #pragma unroll
    for (int mt=0;mt<4;mt++){
      s16x8 afr = Arow[mt][kk*4 + q];
      #pragma unroll
      for (int nt=0;nt<4;nt++)
        acc[mt][nt] = mfma_bf16(afr, bfr[nt], acc[mt][nt]);
    }
  }
  #pragma unroll
  for (int mt=0;mt<4;mt++){
    int mbase = m0 + mt*16 + q*4;
    #pragma unroll
    for (int nt=0;nt<4;nt++){
      int n = n0 + nt*16 + lm;
      if (MODE_C==0){
        #pragma unroll
        for (int r=0;r<4;r++){
          float val = scale*acc[mt][nt][r];
          if (RELU) val = fmaxf(val, 0.f);
          C[(size_t)(mbase+r)*Ntot + n] = f2bf(val);
        }
      } else {
        int tt = mbase>>7, bb = mbase&127;
        int gg = bb>>4;
        s16x4 sv;
        #pragma unroll
        for (int r=0;r<4;r++) sv[r] = (short)f2bf(scale*acc[mt][nt][r]);
        *(s16x4*)(C + (((size_t)tt*8 + gg)*1024 + n)*16 + (bb&15)) = sv;
      }
    }
  }
}

// ---------- LSTM gate activations (inputs scaled by 256) ----------
DEV void lstm_act(const f32x4* A, float* cst, float* hv){
  const float K1 = 1.4426950408889634f/256.f;
  #pragma unroll
  for (int r=0;r<4;r++){
    float iv = frcp_(1.f + fexp2_(-K1*A[0][r]));
    float fv = frcp_(1.f + fexp2_(-K1*A[1][r]));
    float eg = fexp2_(2.f*K1*A[2][r]);
    float gv = (eg-1.f)*frcp_(eg+1.f);
    float ov = frcp_(1.f + fexp2_(-K1*A[3][r]));
    float cv = fv*cst[r] + iv*gv;
    cst[r] = cv;
    float ec = fexp2_(2.8853900817779268f*fminf(cv,30.f));
    hv[r] = ov*(ec-1.f)*frcp_(ec+1.f);
  }
}

// store 4 h values (rows q*4+r) as fp8(16*h) at column j of next h-buffer
DEV void store_h_fp8(unsigned char* hn, int q, const float* hv){
#if __has_builtin(__builtin_amdgcn_cvt_pk_fp8_f32)
  int p01 = __builtin_amdgcn_cvt_pk_fp8_f32(16.f*hv[0], 16.f*hv[1], 0, false);
  int p23 = __builtin_amdgcn_cvt_pk_fp8_f32(16.f*hv[2], 16.f*hv[3], 0, false);
  hn[(q*4+0)*HPB] = (unsigned char)p01;
  hn[(q*4+1)*HPB] = (unsigned char)(p01>>8);
  hn[(q*4+2)*HPB] = (unsigned char)p23;
  hn[(q*4+3)*HPB] = (unsigned char)(p23>>8);
#else
  #pragma unroll
  for (int r=0;r<4;r++) hn[(q*4+r)*HPB] = f2e4m3(16.f*hv[r]);
#endif
}

// ---------- scan1: plain xg1 reads; IMMEDIATE per-step publish (R4-proven) ----------
DEV void scan1_body(unsigned char* smem, const unsigned char* __restrict__ W8,
                    const unsigned short* __restrict__ xg1, unsigned short* __restrict__ hist,
                    int g, unsigned* __restrict__ flags){
  unsigned char*  hl  = smem;                               // 2*16*264 fp8 dbuf
  unsigned short* h1b = (unsigned short*)(smem + 8448);     // [16][272] bf16
  int tid = threadIdx.x;
  int w = tid>>6, l = tid&63, lm = l&15, q = l>>4;
  int j = w*16 + lm;
  for (int i=tid;i<8448;i+=1024) hl[i] = 0;
  long Bf[4][8];
  #pragma unroll
  for (int qq=0;qq<4;qq++){
    int n = qq*256 + j;
    #pragma unroll
    for (int kk=0;kk<8;kk++)
      Bf[qq][kk] = *(const long*)(W8 + (size_t)n*256 + kk*32 + q*8);
  }
  float cst[4] = {0.f,0.f,0.f,0.f};
  const unsigned short* xgb = xg1 + (size_t)g*16384 + q*4;
  s16x4 xc[4], xn[4];
  #pragma unroll
  for (int qq=0;qq<4;qq++) xc[qq] = *(const s16x4*)(xgb + (qq*256+j)*16);
  __syncthreads();
  const unsigned char* hrd = hl + lm*HPB + q*8;
  #pragma unroll 1
  for (int t=0;t<Vx;t++){
    if (t < Vx-1){
      #pragma unroll
      for (int qq=0;qq<4;qq++)
        xn[qq] = *(const s16x4*)(xgb + (size_t)(t+1)*131072 + (qq*256+j)*16);
    }
    const unsigned char* hb = hrd + (t&1)*4224;
    f32x4 A[4];
    #pragma unroll
    for (int qq=0;qq<4;qq++){
      #pragma unroll
      for (int r=0;r<4;r++) A[qq][r] = bf2f((unsigned short)xc[qq][r]);
    }
    #pragma unroll
    for (int kk=0;kk<8;kk++){
      long af = *(const long*)(hb + kk*32);
      A[0] = mfma_fp8(af, Bf[0][kk], A[0]);
      A[1] = mfma_fp8(af, Bf[1][kk], A[1]);
      A[2] = mfma_fp8(af, Bf[2][kk], A[2]);
      A[3] = mfma_fp8(af, Bf[3][kk], A[3]);
    }
    float hv[4];
    lstm_act(A, cst, hv);
    store_h_fp8(hl + ((t+1)&1)*4224 + j, q, hv);
    #pragma unroll
    for (int r=0;r<4;r++) h1b[(q*4+r)*BFP + j] = f2bf(hv[r]);
    lds_barrier();
    {
      int row = tid>>6, c4 = (tid&63)*4;
      s16x4 hx = *(const s16x4*)(h1b + row*BFP + c4);
      astore64(hist + ((size_t)t*Bx + g*16 + row)*Hx + c4, hx);
    }
    vm_drain();                         // immediate per-step publish (R4)
    __syncthreads();
    if (tid == 0) aadd_rlx(&flags[FCT(t)], 1);
    #pragma unroll
    for (int qq=0;qq<4;qq++) xc[qq] = xn[qq];
  }
  if (tid == 0) aadd_rlx(&flags[XDONE], 1);
}

// ---------- scan2: plain xg2 reads (first-touch), 2-deep lookahead ----------
DEV void scan2_body(unsigned char* smem, const unsigned char* __restrict__ W8,
                    const unsigned short* __restrict__ xg2, unsigned short* __restrict__ h2,
                    int g, unsigned* __restrict__ flags){
  unsigned char*  hl  = smem;
  unsigned short* h1b = (unsigned short*)(smem + 8448);
  int tid = threadIdx.x;
  int w = tid>>6, l = tid&63, lm = l&15, q = l>>4;
  int j = w*16 + lm;
  for (int i=tid;i<8448;i+=1024) hl[i] = 0;
  long Bf[4][8];
  #pragma unroll
  for (int qq=0;qq<4;qq++){
    int n = qq*256 + j;
    #pragma unroll
    for (int kk=0;kk<8;kk++)
      Bf[qq][kk] = *(const long*)(W8 + (size_t)n*256 + kk*32 + q*8);
  }
  float cst[4] = {0.f,0.f,0.f,0.f};
  const unsigned short* xgb = xg2 + (size_t)g*16384 + q*4;
  s16x4 xc[4], xn1[4], xn2[4];
  block_wait(&flags[FXG(0)], 1);
  #pragma unroll
  for (int qq=0;qq<4;qq++) xc[qq] = *(const s16x4*)(xgb + (qq*256+j)*16);
  block_wait(&flags[FXG(1)], 1);
  #pragma unroll
  for (int qq=0;qq<4;qq++) xn1[qq] = *(const s16x4*)(xgb + 131072 + (qq*256+j)*16);
  int skip = 0;
  const unsigned char* hrd = hl + lm*HPB + q*8;
  #pragma unroll 1
  for (int t=0;t<Vx;t++){
    if (t+2 < Vx){
      if (tid == 0){
        if (!skip) spin_rlx(&flags[FXG(t+2)], 1);
        skip = (t+3 < Vx) && (aload_rlx(&flags[FXG(t+3)]) >= 1);
      }
      __syncthreads();
      #pragma unroll
      for (int qq=0;qq<4;qq++)
        xn2[qq] = *(const s16x4*)(xgb + (size_t)(t+2)*131072 + (qq*256+j)*16);
    }
    const unsigned char* hb = hrd + (t&1)*4224;
    f32x4 A[4];
    #pragma unroll
    for (int qq=0;qq<4;qq++){
      #pragma unroll
      for (int r=0;r<4;r++) A[qq][r] = bf2f((unsigned short)xc[qq][r]);
    }
    #pragma unroll
    for (int kk=0;kk<8;kk++){
      long af = *(const long*)(hb + kk*32);
      A[0] = mfma_fp8(af, Bf[0][kk], A[0]);
      A[1] = mfma_fp8(af, Bf[1][kk], A[1]);
      A[2] = mfma_fp8(af, Bf[2][kk], A[2]);
      A[3] = mfma_fp8(af, Bf[3][kk], A[3]);
    }
    float hv[4];
    lstm_act(A, cst, hv);
    store_h_fp8(hl + ((t+1)&1)*4224 + j, q, hv);
    if (t == Vx-1){
      #pragma unroll
      for (int r=0;r<4;r++) h1b[(q*4+r)*BFP + j] = f2bf(hv[r]);
      lds_barrier();
      {
        int row = tid>>6, c4 = (tid&63)*4;
        s16x4 hx = *(const s16x4*)(h1b + row*BFP + c4);
        astore64(h2 + (size_t)(g*16 + row)*Hx + c4, hx);
      }
      vm_drain();
      __syncthreads();
      if (tid == 0) aadd_rlx(&flags[XDONE], 1);
    } else {
      lds_barrier();
    }
    #pragma unroll
    for (int qq=0;qq<4;qq++){ xc[qq] = xn1[qq]; xn1[qq] = xn2[qq]; }
  }
}

// xg2 tile GEMM for step `tile`: A rows from LDS (barv) or global v16 (e_k)
template<int ALDS>
DEV void xg2_tile(const unsigned short* Ab, const unsigned short* __restrict__ pool,
                  const float* __restrict__ b_ih, const float* __restrict__ b_hh,
                  unsigned short* __restrict__ xg2, int tile, int w, int lm, int q){
  int mh = (w&1)*64, nb = (w>>1)*128;
  #pragma unroll 1
  for (int sc=0; sc<4; sc++){
    int n0 = nb + sc*32;
    f32x4 acc[4][2];
    #pragma unroll
    for (int nt=0;nt<2;nt++){
      int n = n0 + nt*16 + lm;
      float bz = b_ih[n] + b_hh[n];
      #pragma unroll
      for (int mt=0;mt<4;mt++) acc[mt][nt] = (f32x4){bz,bz,bz,bz};
    }
    #pragma unroll
    for (int kk=0;kk<8;kk++){
      s16x8 bfr[2];
      #pragma unroll
      for (int nt=0;nt<2;nt++){
        int n = n0 + nt*16 + lm;
        bfr[nt] = *(const s16x8*)(pool + PW_IH + (size_t)n*256 + kk*32 + q*8);
      }
      #pragma unroll
      for (int mt=0;mt<4;mt++){
        int row = mh + mt*16 + lm;
        s16x8 afr = ALDS ? *(const s16x8*)(Ab + (size_t)row*WHP + kk*32 + q*8)
                         : *(const s16x8*)(Ab + (size_t)row*Vx*Dx + kk*32 + q*8);
        acc[mt][0] = mfma_bf16(afr, bfr[0], acc[mt][0]);
        acc[mt][1] = mfma_bf16(afr, bfr[1], acc[mt][1]);
      }
    }
    #pragma unroll
    for (int mt=0;mt<4;mt++){
      int m = mh + mt*16 + q*4;
      int gg = m>>4;
      #pragma unroll
      for (int nt=0;nt<2;nt++){
        int n = n0 + nt*16 + lm;
        s16x4 sv;
        #pragma unroll
        for (int r=0;r<4;r++) sv[r] = (short)f2bf(256.f*acc[mt][nt][r]);
        astore64(xg2 + (((size_t)tile*8 + gg)*1024 + n)*16 + (m&15), sv);
      }
    }
  }
}

// ---------- fused worker: wh -> attn -> barv(LDS) -> xg2[t+1] ----------
DEV void worker_body(unsigned short* whs, int t,
    const unsigned short* __restrict__ hist1, const unsigned short* __restrict__ v16,
    const float* __restrict__ u, const unsigned short* __restrict__ pool,
    const float* __restrict__ bhk, const float* __restrict__ W2, const float* __restrict__ b2,
    const float* __restrict__ b_ih, const float* __restrict__ b_hh,
    float* __restrict__ decv, float* __restrict__ genv,
    unsigned short* __restrict__ xg2, unsigned* __restrict__ flags){
  int tid = threadIdx.x, w = tid>>6, l = tid&63, lm = l&15, q = l>>4;
  if (t == 63){
    // xg2[0] from e_k (= v16[:,0,:]) directly; no waits (v16 from prior kernel)
    xg2_tile<0>(v16, pool, b_ih, b_hh, xg2, 0, w, lm, q);
    vm_drain();
    __syncthreads();
    if (tid == 0) astore_rlx(&flags[FXG(0)], 1);
    return;
  }
  block_wait(&flags[FCT(t)], 8);                // scan1 published h[t]
  {
    int r0 = (w&7)*16, n0 = (w>>3)*128;
    const unsigned short* Ar = hist1 + ((size_t)t*Bx + r0 + lm)*Hx;
    f32x4 acc[8];
    #pragma unroll
    for (int nt=0;nt<8;nt++){
      float bz = bhk[n0 + nt*16 + lm];
      acc[nt] = (f32x4){bz,bz,bz,bz};
    }
    #pragma unroll
    for (int kk=0;kk<8;kk++){
      s16x8 afr = *(const s16x8*)(Ar + kk*32 + q*8);   // plain, first-touch
      #pragma unroll
      for (int nt=0;nt<8;nt++){
        int n = n0 + nt*16 + lm;
        s16x8 bfr = *(const s16x8*)(pool + PW_HK + (size_t)n*256 + kk*32 + q*8);
        acc[nt] = mfma_bf16(afr, bfr, acc[nt]);
      }
    }
    #pragma unroll
    for (int nt=0;nt<8;nt++){
      int n = n0 + nt*16 + lm, mb = r0 + q*4;
      #pragma unroll
      for (int r=0;r<4;r++) whs[(size_t)(mb+r)*WHP + n] = f2bf(acc[nt][r]);
    }
  }
  if (tid == 0) spin_med(&flags[FUC], 8);       // one-time event; moderate poll
  __syncthreads();                              // + orders whs stores
  if (w < 8){
    int m0l = w*16;
    f32x4 a2[4];
    #pragma unroll
    for (int nt=0;nt<4;nt++){
      int n = nt*16 + lm;
      #pragma unroll
      for (int r=0;r<4;r++) a2[nt][r] = u[(size_t)(m0l + q*4 + r)*64 + n];
    }
    #pragma unroll
    for (int kk=0;kk<8;kk++){
      s16x8 afr = *(const s16x8*)(whs + (size_t)(m0l+lm)*WHP + kk*32 + q*8);
      #pragma unroll
      for (int nt=0;nt<4;nt++){
        int n = nt*16 + lm;
        s16x8 bfr = *(const s16x8*)(pool + PW_1 + (size_t)n*512 + 256 + kk*32 + q*8);
        a2[nt] = mfma_bf16(afr, bfr, a2[nt]);
      }
    }
    float p0a[4] = {0,0,0,0}, p1a[4] = {0,0,0,0};
    #pragma unroll
    for (int nt=0;nt<4;nt++){
      int n = nt*16 + lm;
      float w2a = W2[n], w2b = W2[64+n];
      #pragma unroll
      for (int r=0;r<4;r++){
        float z = tanh_(a2[nt][r]);
        p0a[r] += z*w2a; p1a[r] += z*w2b;
      }
    }
    #pragma unroll
    for (int s=1;s<16;s<<=1){
      #pragma unroll
      for (int r=0;r<4;r++){ p0a[r] += __shfl_xor(p0a[r], s, 16); p1a[r] += __shfl_xor(p1a[r], s, 16); }
    }
    float bb0 = b2[0], bb1 = b2[1];
    int d0 = lm*16;
    #pragma unroll
    for (int r=0;r<4;r++){
      int b = m0l + q*4 + r;
      float g0 = p0a[r]+bb0, g1 = p1a[r]+bb1;
      float al0 = frcp_(1.f + fexp2_(1.4426950408889634f*(g1-g0)));
      float al1 = 1.f - al0;
      const unsigned short* ek = v16 + (size_t)b*Vx*Dx + d0;
      unsigned short* whp = whs + (size_t)b*WHP + d0;
      size_t ob = ((size_t)b*Vx + (t+1))*Dx + d0;
      #pragma unroll
      for (int c=0;c<2;c++){
        s16x8 e8 = *(const s16x8*)(ek + c*8);
        s16x8 w8 = *(const s16x8*)(whp + c*8);
        s16x8 o16;
        #pragma unroll
        for (int jj=0;jj<8;jj++){
          float o = al0*bf2f((unsigned short)e8[jj]) + al1*bf2f((unsigned short)w8[jj]);
          ntf(decv + ob + c*8 + jj, o);
          ntf(genv + ob + c*8 + jj, o);
          o16[jj] = (short)f2bf(o);
        }
        *(s16x8*)(whp + c*8) = o16;             // barv[t+1] in place
      }
    }
  }
  __syncthreads();                              // barv visible to all waves
  xg2_tile<1>(whs, pool, b_ih, b_hh, xg2, t+1, w, lm, q);
  vm_drain();
  __syncthreads();
  if (tid == 0) astore_rlx(&flags[FXG(t+1)], 1);
}

// ---------- classifier GEMM (tid<256 active; plain A reads post-acquire) ----------
DEV void cls_gemm(const unsigned short* __restrict__ A, const unsigned short* __restrict__ Bw,
                  const float* __restrict__ bias, unsigned short* __restrict__ C,
                  int K, int Ntot, int bxx, int byy){
  int tid = threadIdx.x, w = tid>>6, l = tid&63, lm = l&15, q = l>>4;
  int m0 = bxx*64, n0 = byy*256 + w*64;
  f32x4 acc[4][4];
  #pragma unroll
  for (int nt=0;nt<4;nt++){
    int n = n0 + nt*16 + lm;
    float bz = bias[n];
    #pragma unroll
    for (int mt=0;mt<4;mt++) acc[mt][nt] = (f32x4){bz,bz,bz,bz};
  }
  const s16x8* Arow[4];
  #pragma unroll
  for (int mt=0;mt<4;mt++)
    Arow[mt] = (const s16x8*)(A + (size_t)(m0 + mt*16 + lm)*K);
  int kkn = K/32;
  for (int kk=0; kk<kkn; kk++){
    s16x8 bfr[4];
    #pragma unroll
    for (int nt=0;nt<4;nt++){
      int n = n0 + nt*16 + lm;
      bfr[nt] = *(const s16x8*)(Bw + (size_t)n*K + kk*32 + q*8);
    }
    #pragma unroll
    for (int mt=0;mt<4;mt++){
      s16x8 afr = Arow[mt][kk*4 + q];
      #pragma unroll
      for (int nt=0;nt<4;nt++)
        acc[mt][nt] = mfma_bf16(afr, bfr[nt], acc[mt][nt]);
    }
  }
  #pragma unroll
  for (int mt=0;mt<4;mt++){
    int mbase = m0 + mt*16 + q*4;
    #pragma unroll
    for (int nt=0;nt<4;nt++){
      int n = n0 + nt*16 + lm;
      #pragma unroll
      for (int r=0;r<4;r++)
        astore16(C + (size_t)(mbase+r)*Ntot + n, f2bf(fmaxf(acc[mt][nt][r], 0.f)));
    }
  }
}

// ---------- MEGA: scan1 || workers || scan2 || u || post ----------
__global__ __launch_bounds__(1024) void k_mega(
    const unsigned char* __restrict__ W8,
    unsigned short* __restrict__ xg1, unsigned short* __restrict__ xg2,
    unsigned short* __restrict__ hist1,
    const unsigned short* __restrict__ v16, float* __restrict__ u,
    const unsigned short* __restrict__ pool,
    const float* __restrict__ bhk, const float* __restrict__ W2, const float* __restrict__ b2,
    const float* __restrict__ b1, const float* __restrict__ b_ih, const float* __restrict__ b_hh,
    const float* __restrict__ C1b, const float* __restrict__ C2b, const float* __restrict__ Cob,
    float* __restrict__ decv, float* __restrict__ genv, float* __restrict__ out,
    unsigned* __restrict__ flags){
  __shared__ __align__(16) unsigned char smem[69632];
  int blk = blockIdx.x;
  unsigned short* X  = hist1 + (size_t)(Vx-1)*Bx*Hx;       // [256][256]: h1[63] ; h2
  unsigned short* h2 = hist1 + (size_t)Vx*Bx*Hx;
  unsigned short* y1 = xg1;                                 // overlays (xg1 dead post-scan1)
  unsigned short* y2 = xg1 + 262144;
  if (blk < 8){
    scan1_body(smem, W8, xg1, hist1, blk, flags);
  } else if (blk < 16){
    scan2_body(smem, W8, xg2, h2, blk-8, flags);
  } else if (blk < 80){
    worker_body((unsigned short*)smem, blk-16, hist1, v16, u, pool, bhk, W2, b2,
                b_ih, b_hh, decv, genv, xg2, flags);
  } else if (blk < 88){
    // u GEMV: 8 blocks x 1024 threads = 8192 = 128 b x 64 n
    int t2 = (blk-80)*1024 + threadIdx.x;
    int b = t2>>6, n = t2&63;
    const s16x8* vr = (const s16x8*)(v16 + (size_t)b*Vx*Dx);
    const s16x8* wr = (const s16x8*)(pool + PW_1 + (size_t)n*512);
    float a = b1[n];
    for (int kk=0;kk<32;kk++){
      s16x8 x = vr[kk], ww = wr[kk];
      #pragma unroll
      for (int jj=0;jj<8;jj++) a += bf2f((unsigned short)x[jj])*bf2f((unsigned short)ww[jj]);
    }
    astoref(u + t2, a);
    vm_drain();
    __syncthreads();
    if (threadIdx.x == 0) aadd_rlx(&flags[FUC], 1);
  } else if (blk < 104){
    block_wait_acq_slow(&flags[XDONE], 16);
    int p = blk-88;
    if (threadIdx.x < 256) cls_gemm(X, pool+PC_1, C1b, y1, 256, 1024, p&3, p>>2);
    vm_drain();
    __syncthreads();
    if (threadIdx.x == 0) aadd_rlx(&flags[Y1D], 1);
  } else if (blk < 112){
    block_wait_acq_slow(&flags[Y1D], 16);
    int p = blk-104;
    if (threadIdx.x < 256) cls_gemm(y1, pool+PC_2, C2b, y2, 1024, 512, p&3, p>>2);
    vm_drain();
    __syncthreads();
    if (threadIdx.x == 0) aadd_rlx(&flags[Y2D], 1);
  } else {
    block_wait_acq_slow(&flags[Y2D], 8);
    if (threadIdx.x < 256){
      int t2 = (blk-112)*256 + threadIdx.x;
      int m = t2>>1, n = t2&1;
      const s16x8* yr = (const s16x8*)(y2 + (size_t)m*512);
      const s16x8* wr = (const s16x8*)(pool + PC_O + (size_t)n*512);
      float a = Cob[n];
      for (int kk=0;kk<64;kk++){
        s16x8 yv = yr[kk], ww = wr[kk];
        #pragma unroll
        for (int jj=0;jj<8;jj++) a += bf2f((unsigned short)yv[jj])*bf2f((unsigned short)ww[jj]);
      }
      int base = (m < 128) ? (OFF_OG + m*2) : (OFF_FAKE + (m-128)*2);
      out[base + n] = a;
    }
  }
}

// ---------- launch ----------
extern "C" void kernel_launch(void* const* d_in, const int* in_sizes, int n_in,
                              void* d_out, int out_size, void* d_ws, size_t ws_size,
                              hipStream_t stream) {
  const int*   seqs  = (const int*)d_in[0];
  const float* sts   = (const float*)d_in[3];
  const int*   label = (const int*)d_in[5];
  const float* emb   = (const float*)d_in[6];
  const float* W_ih  = (const float*)d_in[7];
  const float* W_hh  = (const float*)d_in[8];
  const float* b_ih  = (const float*)d_in[9];
  const float* b_hh  = (const float*)d_in[10];
  const float* Whk   = (const float*)d_in[11];
  const float* bhk   = (const float*)d_in[12];
  const float* W1    = (const float*)d_in[13];
  const float* b1    = (const float*)d_in[14];
  const float* W2    = (const float*)d_in[15];
  const float* b2    = (const float*)d_in[16];
  const float* C1b   = (const float*)d_in[18];
  const float* C2b   = (const float*)d_in[20];
  const float* Cob   = (const float*)d_in[22];
  float* out = (float*)d_out;

  char* ws = (char*)d_ws;
  unsigned short* v16    = (unsigned short*)(ws + 0);            //  4 MiB [b][t][d] bf16
  unsigned short* xg1    = (unsigned short*)(ws + (4<<20));      // 16 MiB [t][g][n][16]
  unsigned short* hist1  = (unsigned short*)(ws + (20<<20));     //  4 MiB [t][b][j] + 64K h2
  unsigned short* xg2    = (unsigned short*)(ws + (25<<20));     // 16 MiB [t][g][n][16]
  float*          u      = (float*)(ws + (41<<20));              // 32 KiB
  unsigned char*  whh8   = (unsigned char*)(ws + (41<<20) + (64<<10));   // 256 KiB
  unsigned*       flags  = (unsigned*)(ws + (41<<20) + (384<<10));       // 32 KiB
  unsigned short* pool   = (unsigned short*)(ws + (42<<20));     // 2.82 MiB

  float* decv = out + OFF_DECV;
  float* genv = out + OFF_GENV;

  k_pre<<<dim3(14725), dim3(256), 0, stream>>>(seqs, emb, v16, decv, genv,
      W_ih, W_hh, Whk, W1, (const float*)d_in[17], (const float*)d_in[19],
      (const float*)d_in[21], pool, whh8, sts, label, out, flags);
  k_gemm<1,1,0><<<dim3(128,4), dim3(256), 0, stream>>>(v16, pool+PW_IH, b_ih, b_hh, xg1, 256, 1024, 256.f);
  k_mega<<<dim3(114), dim3(1024), 0, stream>>>(whh8, xg1, xg2, hist1, v16, u, pool,
      bhk, W2, b2, b1, b_ih, b_hh, C1b, C2b, Cob, decv, genv, out, flags);
}